// Round 8
// baseline (458.932 us; speedup 1.0000x reference)
//
#include <hip/hip_runtime.h>

// Problem constants (fixed by the reference)
#define Bn 2
#define Nn 256
#define Mn 512
#define Cn 256
#define Hn 8
#define MT 64             // m-tile size in fused kernel
#define SCALE_ 0.17677669529663687f   // Dh^-0.5, Dh=32
#define INV2PI 0.15915494309189535f

typedef short bf16x8 __attribute__((ext_vector_type(8)));
typedef short bf16x4 __attribute__((ext_vector_type(4)));
typedef float f32x4 __attribute__((ext_vector_type(4)));

static __device__ __forceinline__ float b2f(short s) {
    unsigned u = ((unsigned)(unsigned short)s) << 16;
    return __builtin_bit_cast(float, u);
}
static __device__ __forceinline__ short f2b(float f) {   // RNE f32->bf16
    unsigned u = __builtin_bit_cast(unsigned, f);
    u += 0x7fffu + ((u >> 16) & 1u);
    return (short)(u >> 16);
}
static __device__ __forceinline__ void async16(const void* g, void* l) {
    __builtin_amdgcn_global_load_lds(
        (const __attribute__((address_space(1))) unsigned int*)g,
        (__attribute__((address_space(3))) unsigned int*)l, 16, 0, 0);
}

// ---- prep: W1/W2 convert + q'/k'/v' projections ----
// bid 0..255: convert. 256..511: q' (8rx64c, f32). 512..767: k' (32rx32c,
// bf16 TRANSPOSED [b][c][m]). 768..1023: v' (bf16 PLAIN [b][m][c]).
__global__ __launch_bounds__(256) void prep(
        const float* __restrict__ query, const float* __restrict__ key,
        const float* __restrict__ Wq, const float* __restrict__ bq,
        const float* __restrict__ Wk, const float* __restrict__ Wv,
        const float* __restrict__ bv, const float* __restrict__ W1,
        const float* __restrict__ W2, short* __restrict__ W1b,
        short* __restrict__ W2b, float* __restrict__ qp,
        short* __restrict__ kTb, short* __restrict__ vpb) {
    __shared__ float arow[32][Cn];
    const int bid = blockIdx.x;
    const int t = threadIdx.x;
    if (bid < 256) {                       // convert W1/W2 to bf16
        const int i = bid * 256 + t;
        W1b[i] = f2b(W1[i]);
        W2b[i] = f2b(W2[i]);
        return;
    }
    if (bid < 512) {                       // q': 8 rows x 64 cols
        const int id = bid - 256;
        const int r0 = (id >> 2) * 8, c0 = (id & 3) * 64;
        #pragma unroll
        for (int i = 0; i < 8; ++i) arow[i][t] = query[(size_t)(r0 + i) * Cn + t];
        __syncthreads();
        const int col = c0 + (t & 63);
        const int rs = t >> 6;             // 4 slots x 2 rows
        float a0 = 0.f, a1 = 0.f;
        const float* wr = Wq + (size_t)col * Cn;
        for (int k = 0; k < Cn; k += 4) {
            const float4 wv = *(const float4*)(wr + k);
            const int r = rs * 2;
            a0 += arow[r][k] * wv.x + arow[r][k+1] * wv.y
                + arow[r][k+2] * wv.z + arow[r][k+3] * wv.w;
            a1 += arow[r+1][k] * wv.x + arow[r+1][k+1] * wv.y
                + arow[r+1][k+2] * wv.z + arow[r+1][k+3] * wv.w;
        }
        const float bvv = bq[col];
        qp[(size_t)(r0 + rs * 2) * Cn + col] = a0 + bvv;
        qp[(size_t)(r0 + rs * 2 + 1) * Cn + col] = a1 + bvv;
        return;
    }
    // k'/v': 32 rows x 32 cols
    const int isv = bid >= 768;
    const int id = bid - (isv ? 768 : 512);
    const int r0 = (id >> 3) * 32, c0 = (id & 7) * 32;
    const float* W = isv ? Wv : Wk;
    #pragma unroll
    for (int i = 0; i < 32; ++i) arow[i][t] = key[(size_t)(r0 + i) * Cn + t];
    __syncthreads();
    const int col = c0 + (t & 31);
    const int rs = t >> 5;                 // 8 slots x 4 rows
    float a4[4] = {0.f, 0.f, 0.f, 0.f};
    const float* wr = W + (size_t)col * Cn;
    for (int k = 0; k < Cn; k += 4) {
        const float4 wv = *(const float4*)(wr + k);
        #pragma unroll
        for (int i = 0; i < 4; ++i) {
            const int r = rs * 4 + i;
            a4[i] += arow[r][k] * wv.x + arow[r][k+1] * wv.y
                   + arow[r][k+2] * wv.z + arow[r][k+3] * wv.w;
        }
    }
    if (!isv) {
        const int bk = r0 >> 9, mloc = (r0 & 511) + rs * 4;
        bf16x4 p;
        #pragma unroll
        for (int i = 0; i < 4; ++i) p[i] = f2b(a4[i]);
        *(bf16x4*)(kTb + (size_t)(bk * Cn + col) * Mn + mloc) = p;   // transposed
    } else {
        const float bvv = bv[col];
        #pragma unroll
        for (int i = 0; i < 4; ++i)
            vpb[(size_t)(r0 + rs * 4 + i) * Cn + col] = f2b(a4[i] + bvv);  // plain
    }
}

// ---- fused attention + out-projection ----
// 512 threads = 8 waves; wave w owns channel slice [w*32, w*32+32) == head w.
// LDS 72.6 KB -> exactly 2 blocks/CU; waves_per_eu(4,4) -> 128-VGPR budget.
__global__ __launch_bounds__(512)
__attribute__((amdgpu_waves_per_eu(4, 4)))
void fused_attn(
        const float* __restrict__ qp, const short* __restrict__ kTb,
        const short* __restrict__ vpb, const float* __restrict__ qpos,
        const short* __restrict__ W1b, const short* __restrict__ W2b,
        const float* __restrict__ b1, const float* __restrict__ b2,
        const float* __restrict__ freqs, const float* __restrict__ Wo,
        const float* __restrict__ bo, const float* __restrict__ query,
        float* __restrict__ xout) {
    __shared__ __align__(16) char embS[MT * 512];   // 32 KB emb/S, XOR-swizzled
    __shared__ __align__(16) char vS[MT * 512];     // 32 KB V tile bf16 [m][c]
    __shared__ float tposS[Mn];                     // 2 KB qpos row
    __shared__ float fbuf[128];                     // freqs / 2pi
    __shared__ float qbuf[Cn], b2buf[Cn];           // q' row, b2
    __shared__ float scb2[Hn * MT];                 // scores -> weights -> x
    __shared__ float pacc[512];
    __shared__ float corrS[Hn], lS[Hn];

    const int t = threadIdx.x;
    const int lane = t & 63;
    const int w = t >> 6;                 // wave id = head id = col-slice id
    const int lr = lane & 15, lg = lane >> 4;

    // XCD-chunked bijective swizzle: 512 blocks = 8 XCDs x 64 contiguous
    const int qrow = ((blockIdx.x & 7) << 6) | (blockIdx.x >> 3);
    const int b = qrow >> 8;              // batch

    const int cA = w * 32 + lr, cB = cA + 16;
    const short* w1p0 = W1b + (size_t)cA * Cn + lg * 8;
    const short* w1p1 = W1b + (size_t)cB * Cn + lg * 8;
    const short* w2p0 = W2b + (size_t)cA * Cn + lg * 8;
    const short* w2p1 = W2b + (size_t)cB * Cn + lg * 8;

    // time-shared W fragment buffer (64 VGPRs): W1 for GEMM1, W2 for GEMM2
    bf16x8 wreg[16];
    #pragma unroll
    for (int kk = 0; kk < 8; ++kk) {
        wreg[kk] = *(const bf16x8*)(w1p0 + kk * 32);
        wreg[8 + kk] = *(const bf16x8*)(w1p1 + kk * 32);
    }

    const float b1v0 = b1[cA], b1v1 = b1[cB];
    tposS[t] = qpos[(size_t)qrow * Mn + t];
    if (t < 128) fbuf[t] = freqs[t] * INV2PI;
    if (t < 256) { qbuf[t] = qp[(size_t)qrow * Cn + t]; b2buf[t] = b2[t]; }
    float m_run = -1e30f, l_run = 0.f;
    float xacc = 0.f;                     // t<256: output channel t
    const f32x4 vzero = {0.f, 0.f, 0.f, 0.f};
    const short* kbb = kTb + (size_t)b * Cn * Mn;   // k' [c][m] base for batch
    __syncthreads();

    for (int m0 = 0; m0 < Mn; m0 += MT) {
        // issue async V tile (plain [m][c], linear LDS dest)
        {
            const size_t tbase = ((size_t)(b * Mn + m0)) * Cn;   // elem offset
            #pragma unroll
            for (int i = 0; i < 4; ++i) {
                const int seg = (i * 8 + w) * 1024;   // bytes
                async16((const char*)vpb + tbase * 2 + seg + lane * 16, vS + seg);
            }
        }

        // phase 1: embeddings -> embS. thread: m = t>>3, freq group fg = t&7
        {
            const int m = t >> 3, fg = t & 7;
            const float tv = tposS[m0 + m];
            bf16x8 pc[2], ps[2];
            #pragma unroll
            for (int j = 0; j < 16; ++j) {
                const float xr = tv * fbuf[fg * 16 + j];
                pc[j >> 3][j & 7] = f2b(__builtin_amdgcn_cosf(xr));
                ps[j >> 3][j & 7] = f2b(__builtin_amdgcn_sinf(xr));
            }
            char* rowp = embS + m * 512;
            const int sw = (m & 7) << 4;
            *(bf16x8*)(rowp + ((fg * 32) ^ sw)) = pc[0];        // cos -> [0:128)
            *(bf16x8*)(rowp + ((fg * 32 + 16) ^ sw)) = pc[1];
            *(bf16x8*)(rowp + ((256 + fg * 32) ^ sw)) = ps[0];  // sin -> [128:256)
            *(bf16x8*)(rowp + ((256 + fg * 32 + 16) ^ sw)) = ps[1];
        }
        __syncthreads();                  // (A) emb + V visible

        // phase 2: GEMM1  hidden = emb @ W1^T
        f32x4 acc[4][2];
        #pragma unroll
        for (int pb = 0; pb < 4; ++pb) { acc[pb][0] = vzero; acc[pb][1] = vzero; }
        #pragma unroll
        for (int pb = 0; pb < 4; ++pb) {
            const int row = pb * 16 + lr;
            const int sw = (row & 7) << 4;
            const char* rowp = embS + row * 512;
            #pragma unroll
            for (int kk = 0; kk < 8; ++kk) {
                const bf16x8 a = *(const bf16x8*)(rowp + ((lg * 16 + kk * 64) ^ sw));
                acc[pb][0] = __builtin_amdgcn_mfma_f32_16x16x32_bf16(a, wreg[kk],     acc[pb][0], 0, 0, 0);
                acc[pb][1] = __builtin_amdgcn_mfma_f32_16x16x32_bf16(a, wreg[8 + kk], acc[pb][1], 0, 0, 0);
            }
        }
        // refill wreg with W2 (drain overlaps silu)
        #pragma unroll
        for (int kk = 0; kk < 8; ++kk) {
            wreg[kk] = *(const bf16x8*)(w2p0 + kk * 32);
            wreg[8 + kk] = *(const bf16x8*)(w2p1 + kk * 32);
        }
        __syncthreads();                  // (B) all emb reads done

        // store S = silu(hidden + b1) into embS (swizzled)
        #pragma unroll
        for (int pb = 0; pb < 4; ++pb) {
            #pragma unroll
            for (int jb = 0; jb < 2; ++jb) {
                const float bv = jb ? b1v1 : b1v0;
                const int j = w * 32 + jb * 16 + lr;
                #pragma unroll
                for (int r = 0; r < 4; ++r) {
                    const int row = pb * 16 + lg * 4 + r;   // C/D: row = 4*(lane>>4)+reg
                    float hv = acc[pb][jb][r] + bv;
                    hv = hv / (1.f + __expf(-hv));
                    *(short*)(embS + row * 512 + ((j * 2) ^ ((row & 7) << 4))) = f2b(hv);
                }
            }
        }
        __syncthreads();                  // (C) S visible

        // phase 3: SWAPPED GEMM2  D2 = W2slice @ S^T  (+b2 via acc init)
        // lane (lr,lg) reg r of acc[mb][cb]: D2[c = w*32+cb*16+lg*4+r][m = mb*16+lr]
        #pragma unroll
        for (int mb = 0; mb < 4; ++mb)
            #pragma unroll
            for (int cb = 0; cb < 2; ++cb)
                #pragma unroll
                for (int r = 0; r < 4; ++r)
                    acc[mb][cb][r] = b2buf[w * 32 + cb * 16 + lg * 4 + r];
        #pragma unroll
        for (int mb = 0; mb < 4; ++mb) {
            const int row = mb * 16 + lr;
            const int sw = (row & 7) << 4;
            const char* rowp = embS + row * 512;
            #pragma unroll
            for (int kk = 0; kk < 8; ++kk) {
                const bf16x8 a = *(const bf16x8*)(rowp + ((lg * 16 + kk * 64) ^ sw));
                acc[mb][0] = __builtin_amdgcn_mfma_f32_16x16x32_bf16(wreg[kk],     a, acc[mb][0], 0, 0, 0);
                acc[mb][1] = __builtin_amdgcn_mfma_f32_16x16x32_bf16(wreg[8 + kk], a, acc[mb][1], 0, 0, 0);
            }
        }
        // refill wreg with W1 for next tile (in-flight through phases 4-6)
        #pragma unroll
        for (int kk = 0; kk < 8; ++kk) {
            wreg[kk] = *(const bf16x8*)(w1p0 + kk * 32);
            wreg[8 + kk] = *(const bf16x8*)(w1p1 + kk * 32);
        }

        // phase 4: s[m] = SCALE * sum_c q[c]*k[m][c]*D2[c][m]; reduce over lg (2 shfl)
        #pragma unroll
        for (int mb = 0; mb < 4; ++mb) {
            const int m = mb * 16 + lr;
            const short* kb = kbb + m0 + m;
            float partial = 0.f;
            #pragma unroll
            for (int cb = 0; cb < 2; ++cb) {
                #pragma unroll
                for (int r = 0; r < 4; ++r) {
                    const int c = w * 32 + cb * 16 + lg * 4 + r;
                    partial += b2f(kb[(size_t)c * Mn]) * qbuf[c] * acc[mb][cb][r];
                }
            }
            partial += __shfl_xor(partial, 16);
            partial += __shfl_xor(partial, 32);
            if (lg == 0) scb2[w * MT + m] = partial * SCALE_;
        }

        // phase 5: wave-local online softmax for head w
        {
            const float s = scb2[w * MT + lane];
            float tmax = s;
            #pragma unroll
            for (int msk = 1; msk < 64; msk <<= 1) tmax = fmaxf(tmax, __shfl_xor(tmax, msk));
            const float mnew = fmaxf(m_run, tmax);
            const float corr = __expf(m_run - mnew);
            const float e = __expf(s - mnew);
            scb2[w * MT + lane] = e;
            float ss = e;
            #pragma unroll
            for (int msk = 1; msk < 64; msk <<= 1) ss += __shfl_xor(ss, msk);
            l_run = l_run * corr + ss;
            m_run = mnew;
            if (lane == 0) corrS[w] = corr;
        }
        __syncthreads();                  // (D) weights + corrS visible

        // phase 6: PV partials from vS. thread: c = t&255, m-half = t>>8
        {
            const int c = t & 255, half = t >> 8;
            const int h = c >> 5;
            const char* vb = vS + (half * 32) * 512 + c * 2;
            const float* wr2 = scb2 + h * MT + half * 32;
            float s = 0.f;
            #pragma unroll
            for (int i = 0; i < 8; ++i) {
                const float4 wa = *(const float4*)(wr2 + i * 4);
                s += wa.x * b2f(*(const short*)(vb + (i * 4 + 0) * 512))
                   + wa.y * b2f(*(const short*)(vb + (i * 4 + 1) * 512))
                   + wa.z * b2f(*(const short*)(vb + (i * 4 + 2) * 512))
                   + wa.w * b2f(*(const short*)(vb + (i * 4 + 3) * 512));
            }
            pacc[t] = s;
        }
        __syncthreads();                  // (E) pacc visible
        if (t < 256) xacc = xacc * corrS[t >> 5] + pacc[t] + pacc[t + 256];
    }

    // epilogue: finish softmax norm, then fused out-projection + residual
    if (lane == 0) lS[w] = l_run;
    __syncthreads();
    if (t < 256) scb2[t] = xacc / lS[t >> 5];    // x vector (256 f32)
    __syncthreads();
    {
        const int j = t & 255, half = t >> 8;
        const float* wr = Wo + (size_t)j * Cn + half * 128;
        const float* xb = scb2 + half * 128;
        float s = 0.f;
        for (int k = 0; k < 128; k += 4) {
            const float4 wv = *(const float4*)(wr + k);
            s += xb[k] * wv.x + xb[k+1] * wv.y + xb[k+2] * wv.z + xb[k+3] * wv.w;
        }
        pacc[t] = s;
    }
    __syncthreads();
    if (t < 256)
        xout[(size_t)qrow * Cn + t] = pacc[t] + pacc[t + 256] + bo[t]
                                    + query[(size_t)qrow * Cn + t];
}

extern "C" void kernel_launch(void* const* d_in, const int* in_sizes, int n_in,
                              void* d_out, int out_size, void* d_ws, size_t ws_size,
                              hipStream_t stream) {
    const float* query = (const float*)d_in[0];
    const float* key   = (const float*)d_in[1];
    const float* qpos  = (const float*)d_in[2];
    const float* Wq    = (const float*)d_in[3];
    const float* bq    = (const float*)d_in[4];
    const float* Wk    = (const float*)d_in[5];
    const float* Wv    = (const float*)d_in[6];
    const float* bv    = (const float*)d_in[7];
    const float* Wo    = (const float*)d_in[8];
    const float* bo    = (const float*)d_in[9];
    const float* W1    = (const float*)d_in[10];
    const float* b1    = (const float*)d_in[11];
    const float* W2    = (const float*)d_in[12];
    const float* b2    = (const float*)d_in[13];
    const float* freqs = (const float*)d_in[14];
    float* out = (float*)d_out;

    char* ws = (char*)d_ws;
    float* qp  = (float*)(ws);                 // 512 KB  (B*N*C f32)
    short* kTb = (short*)(ws + 524288);        // 512 KB  (B*C*M bf16, transposed)
    short* vpb = (short*)(ws + 1048576);       // 512 KB  (B*M*C bf16, plain)
    short* W1b = (short*)(ws + 1572864);       // 128 KB bf16
    short* W2b = (short*)(ws + 1703936);       // 128 KB bf16

    prep<<<1024, 256, 0, stream>>>(query, key, Wq, bq, Wk, Wv, bv, W1, W2,
                                   W1b, W2b, qp, kTb, vpb);
    fused_attn<<<Bn * Nn, 512, 0, stream>>>(qp, kTb, vpb, qpos, W1b, W2b,
                                            b1, b2, freqs, Wo, bo, query, out);
}

// Round 9
// 325.824 us; speedup vs baseline: 1.4085x; 1.4085x over previous
//
#include <hip/hip_runtime.h>

// Problem constants (fixed by the reference)
#define Bn 2
#define Nn 256
#define Mn 512
#define Cn 256
#define Hn 8
#define MT 64             // m-tile size in fused kernel
#define SCALE_ 0.17677669529663687f   // Dh^-0.5, Dh=32
#define INV2PI 0.15915494309189535f

typedef short bf16x8 __attribute__((ext_vector_type(8)));
typedef short bf16x4 __attribute__((ext_vector_type(4)));
typedef float f32x4 __attribute__((ext_vector_type(4)));

static __device__ __forceinline__ float b2f(short s) {
    unsigned u = ((unsigned)(unsigned short)s) << 16;
    return __builtin_bit_cast(float, u);
}
static __device__ __forceinline__ short f2b(float f) {   // RNE f32->bf16
    unsigned u = __builtin_bit_cast(unsigned, f);
    u += 0x7fffu + ((u >> 16) & 1u);
    return (short)(u >> 16);
}
static __device__ __forceinline__ void async16(const void* g, void* l) {
    __builtin_amdgcn_global_load_lds(
        (const __attribute__((address_space(1))) unsigned int*)g,
        (__attribute__((address_space(3))) unsigned int*)l, 16, 0, 0);
}

// ---- prep: W1/W2 convert + q'/k'/v' projections ----
// bid 0..255: convert. 256..511: q' (8rx64c, f32).
// 512..767: k', 768..1023: v' -- both bf16 [b][m][c] with per-row XOR swizzle
// (byte_in_row = c*2 ^ ((m&7)<<4)) so async16 linear copies land pre-swizzled.
__global__ __launch_bounds__(256) void prep(
        const float* __restrict__ query, const float* __restrict__ key,
        const float* __restrict__ Wq, const float* __restrict__ bq,
        const float* __restrict__ Wk, const float* __restrict__ Wv,
        const float* __restrict__ bv, const float* __restrict__ W1,
        const float* __restrict__ W2, short* __restrict__ W1b,
        short* __restrict__ W2b, float* __restrict__ qp,
        short* __restrict__ kpb, short* __restrict__ vpb) {
    __shared__ float arow[32][Cn];
    const int bid = blockIdx.x;
    const int t = threadIdx.x;
    if (bid < 256) {                       // convert W1/W2 to bf16
        const int i = bid * 256 + t;
        W1b[i] = f2b(W1[i]);
        W2b[i] = f2b(W2[i]);
        return;
    }
    if (bid < 512) {                       // q': 8 rows x 64 cols
        const int id = bid - 256;
        const int r0 = (id >> 2) * 8, c0 = (id & 3) * 64;
        #pragma unroll
        for (int i = 0; i < 8; ++i) arow[i][t] = query[(size_t)(r0 + i) * Cn + t];
        __syncthreads();
        const int col = c0 + (t & 63);
        const int rs = t >> 6;             // 4 slots x 2 rows
        float a0 = 0.f, a1 = 0.f;
        const float* wr = Wq + (size_t)col * Cn;
        for (int k = 0; k < Cn; k += 4) {
            const float4 wv = *(const float4*)(wr + k);
            const int r = rs * 2;
            a0 += arow[r][k] * wv.x + arow[r][k+1] * wv.y
                + arow[r][k+2] * wv.z + arow[r][k+3] * wv.w;
            a1 += arow[r+1][k] * wv.x + arow[r+1][k+1] * wv.y
                + arow[r+1][k+2] * wv.z + arow[r+1][k+3] * wv.w;
        }
        const float bvv = bq[col];
        qp[(size_t)(r0 + rs * 2) * Cn + col] = a0 + bvv;
        qp[(size_t)(r0 + rs * 2 + 1) * Cn + col] = a1 + bvv;
        return;
    }
    // k'/v': 32 rows x 32 cols, swizzled [b][m][c] bf16 out
    const int isv = bid >= 768;
    const int id = bid - (isv ? 768 : 512);
    const int r0 = (id >> 3) * 32, c0 = (id & 7) * 32;
    const float* W = isv ? Wv : Wk;
    short* outb = isv ? vpb : kpb;
    #pragma unroll
    for (int i = 0; i < 32; ++i) arow[i][t] = key[(size_t)(r0 + i) * Cn + t];
    __syncthreads();
    const int col = c0 + (t & 31);
    const int rs = t >> 5;                 // 8 slots x 4 rows
    float a4[4] = {0.f, 0.f, 0.f, 0.f};
    const float* wr = W + (size_t)col * Cn;
    for (int k = 0; k < Cn; k += 4) {
        const float4 wv = *(const float4*)(wr + k);
        #pragma unroll
        for (int i = 0; i < 4; ++i) {
            const int r = rs * 4 + i;
            a4[i] += arow[r][k] * wv.x + arow[r][k+1] * wv.y
                   + arow[r][k+2] * wv.z + arow[r][k+3] * wv.w;
        }
    }
    const float bvv = isv ? bv[col] : 0.f;
    const int bk = r0 >> 9, m0 = (r0 & 511) + rs * 4;
    char* base = (char*)outb + (size_t)bk * Mn * Cn * 2;
    #pragma unroll
    for (int i = 0; i < 4; ++i) {
        const int m = m0 + i;
        *(short*)(base + m * 512 + ((col * 2) ^ ((m & 7) << 4))) = f2b(a4[i] + bvv);
    }
}

// ---- fused attention + out-projection ----
// 512 threads = 8 waves; wave w owns channel slice [w*32, w*32+32) == head w.
// LDS ~105 KB -> 1 block/CU; waves_per_eu(2,2) -> 128 arch VGPRs (+128 agpr).
// Time-shared wreg[16] (64 regs) leaves ~60 arch regs for temps -> no spill.
__global__ __launch_bounds__(512)
__attribute__((amdgpu_waves_per_eu(2, 2)))
void fused_attn(
        const float* __restrict__ qp, const short* __restrict__ kpb,
        const short* __restrict__ vpb, const float* __restrict__ qpos,
        const short* __restrict__ W1b, const short* __restrict__ W2b,
        const float* __restrict__ b1, const float* __restrict__ b2,
        const float* __restrict__ freqs, const float* __restrict__ Wo,
        const float* __restrict__ bo, const float* __restrict__ query,
        float* __restrict__ xout) {
    __shared__ __align__(16) char embS[MT * 512];   // 32 KB emb/S, XOR-swizzled
    __shared__ __align__(16) char kS[MT * 512];     // 32 KB K tile bf16 [m][c] swz
    __shared__ __align__(16) char vS[MT * 512];     // 32 KB V tile bf16 [m][c] swz
    __shared__ float tposS[Mn];                     // 2 KB qpos row
    __shared__ float fbuf[128];                     // freqs / 2pi
    __shared__ float scb2[Hn * MT];                 // scores -> weights -> x
    __shared__ float pacc[512];
    __shared__ float corrS[Hn], lS[Hn];

    const int t = threadIdx.x;
    const int lane = t & 63;
    const int w = t >> 6;                 // wave id = head id = col-slice id
    const int lr = lane & 15, lg = lane >> 4;

    // XCD-chunked bijective swizzle: 512 blocks = 8 XCDs x 64 contiguous
    const int qrow = ((blockIdx.x & 7) << 6) | (blockIdx.x >> 3);
    const int b = qrow >> 8;              // batch

    const int cA = w * 32 + lr, cB = cA + 16;
    const short* w1p0 = W1b + (size_t)cA * Cn + lg * 8;
    const short* w1p1 = W1b + (size_t)cB * Cn + lg * 8;
    const short* w2p0 = W2b + (size_t)cA * Cn + lg * 8;
    const short* w2p1 = W2b + (size_t)cB * Cn + lg * 8;

    // time-shared W fragment buffer (64 VGPRs): W1 for GEMM1, W2 for GEMM2
    bf16x8 wreg[16];
    #pragma unroll
    for (int kk = 0; kk < 8; ++kk) {
        wreg[kk] = *(const bf16x8*)(w1p0 + kk * 32);
        wreg[8 + kk] = *(const bf16x8*)(w1p1 + kk * 32);
    }

    const float b1v0 = b1[cA], b1v1 = b1[cB];
    // q' (scaled) and b2 slices for the swapped-GEMM2 lane mapping:
    // index i = cb*4+r -> channel c = w*32 + cb*16 + lg*4 + r
    float qr[8], b2r[8];
    #pragma unroll
    for (int i = 0; i < 8; ++i) {
        const int c = w * 32 + (i >> 2) * 16 + lg * 4 + (i & 3);
        qr[i] = qp[(size_t)qrow * Cn + c] * SCALE_;
        b2r[i] = b2[c];
    }
    tposS[t] = qpos[(size_t)qrow * Mn + t];
    if (t < 128) fbuf[t] = freqs[t] * INV2PI;
    float m_run = -1e30f, l_run = 0.f;
    float xacc = 0.f;                     // t<256: output channel t
    __syncthreads();

    for (int m0 = 0; m0 < Mn; m0 += MT) {
        // issue async K/V tile loads (linear LDS dest; global is pre-swizzled)
        {
            const size_t tbase = ((size_t)(b * Mn + m0)) * Cn * 2;   // bytes
            #pragma unroll
            for (int i = 0; i < 4; ++i) {
                const int seg = (i * 8 + w) * 1024;
                async16((const char*)kpb + tbase + seg + lane * 16, kS + seg);
                async16((const char*)vpb + tbase + seg + lane * 16, vS + seg);
            }
        }

        // phase 1: embeddings -> embS. thread: m = t>>3, freq group fg = t&7
        // v_sin/v_cos take revolutions; args < 0.16 rev -> no range reduction.
        {
            const int m = t >> 3, fg = t & 7;
            const float tv = tposS[m0 + m];
            bf16x8 pc[2], ps[2];
            #pragma unroll
            for (int j = 0; j < 16; ++j) {
                const float xr = tv * fbuf[fg * 16 + j];
                pc[j >> 3][j & 7] = f2b(__builtin_amdgcn_cosf(xr));
                ps[j >> 3][j & 7] = f2b(__builtin_amdgcn_sinf(xr));
            }
            char* rowp = embS + m * 512;
            const int sw = (m & 7) << 4;
            *(bf16x8*)(rowp + ((fg * 32) ^ sw)) = pc[0];        // cos -> [0:128)
            *(bf16x8*)(rowp + ((fg * 32 + 16) ^ sw)) = pc[1];
            *(bf16x8*)(rowp + ((256 + fg * 32) ^ sw)) = ps[0];  // sin -> [128:256)
            *(bf16x8*)(rowp + ((256 + fg * 32 + 16) ^ sw)) = ps[1];
        }
        __syncthreads();                  // (A) emb + staged K/V visible

        // phase 2: GEMM1  hidden = emb @ W1^T
        f32x4 acc[4][2];
        #pragma unroll
        for (int pb = 0; pb < 4; ++pb) {
            acc[pb][0] = (f32x4){0.f, 0.f, 0.f, 0.f};
            acc[pb][1] = (f32x4){0.f, 0.f, 0.f, 0.f};
        }
        #pragma unroll
        for (int pb = 0; pb < 4; ++pb) {
            const int row = pb * 16 + lr;
            const int sw = (row & 7) << 4;
            const char* rowp = embS + row * 512;
            #pragma unroll
            for (int kk = 0; kk < 8; ++kk) {
                const bf16x8 a = *(const bf16x8*)(rowp + ((lg * 16 + kk * 64) ^ sw));
                acc[pb][0] = __builtin_amdgcn_mfma_f32_16x16x32_bf16(a, wreg[kk],     acc[pb][0], 0, 0, 0);
                acc[pb][1] = __builtin_amdgcn_mfma_f32_16x16x32_bf16(a, wreg[8 + kk], acc[pb][1], 0, 0, 0);
            }
        }
        // refill wreg with W2 (L2; drain overlaps silu)
        #pragma unroll
        for (int kk = 0; kk < 8; ++kk) {
            wreg[kk] = *(const bf16x8*)(w2p0 + kk * 32);
            wreg[8 + kk] = *(const bf16x8*)(w2p1 + kk * 32);
        }
        __syncthreads();                  // (B) all emb reads done

        // store S = silu(hidden + b1) into embS (swizzled)
        #pragma unroll
        for (int pb = 0; pb < 4; ++pb) {
            #pragma unroll
            for (int jb = 0; jb < 2; ++jb) {
                const float bv = jb ? b1v1 : b1v0;
                const int j = w * 32 + jb * 16 + lr;
                #pragma unroll
                for (int r = 0; r < 4; ++r) {
                    const int row = pb * 16 + lg * 4 + r;   // C/D: row = 4*(lane>>4)+reg
                    float hv = acc[pb][jb][r] + bv;
                    hv = hv / (1.f + __expf(-hv));
                    *(short*)(embS + row * 512 + ((j * 2) ^ ((row & 7) << 4))) = f2b(hv);
                }
            }
        }
        __syncthreads();                  // (C) S visible

        // phase 3: SWAPPED GEMM2  D2 = W2slice @ S^T  (+b2 via acc init)
        // lane (lr,lg) reg r of acc[mb][cb]: D2[c = w*32+cb*16+lg*4+r][m = mb*16+lr]
        #pragma unroll
        for (int mb = 0; mb < 4; ++mb)
            #pragma unroll
            for (int cb = 0; cb < 2; ++cb)
                #pragma unroll
                for (int r = 0; r < 4; ++r)
                    acc[mb][cb][r] = b2r[cb * 4 + r];
        #pragma unroll
        for (int mb = 0; mb < 4; ++mb) {
            const int row = mb * 16 + lr;
            const int sw = (row & 7) << 4;
            const char* rowp = embS + row * 512;
            #pragma unroll
            for (int kk = 0; kk < 8; ++kk) {
                const bf16x8 a = *(const bf16x8*)(rowp + ((lg * 16 + kk * 64) ^ sw));
                acc[mb][0] = __builtin_amdgcn_mfma_f32_16x16x32_bf16(wreg[kk],     a, acc[mb][0], 0, 0, 0);
                acc[mb][1] = __builtin_amdgcn_mfma_f32_16x16x32_bf16(wreg[8 + kk], a, acc[mb][1], 0, 0, 0);
            }
        }
        // refill wreg with W1 for next tile (drains during phases 4-6)
        #pragma unroll
        for (int kk = 0; kk < 8; ++kk) {
            wreg[kk] = *(const bf16x8*)(w1p0 + kk * 32);
            wreg[8 + kk] = *(const bf16x8*)(w1p1 + kk * 32);
        }

        // phase 4: s[m] = sum_c q[c]*k[m][c]*D2[c][m]; K from kS (b64 reads);
        // reduce over lg = 2 shuffles
        #pragma unroll
        for (int mb = 0; mb < 4; ++mb) {
            const int m = mb * 16 + lr;
            const int sw = (m & 7) << 4;
            const char* kr = kS + m * 512;
            const int c0 = (w * 32 + lg * 4) * 2;
            const bf16x4 k0 = *(const bf16x4*)(kr + (c0 ^ sw));
            const bf16x4 k1 = *(const bf16x4*)(kr + ((c0 + 32) ^ sw));
            float partial = 0.f;
            #pragma unroll
            for (int r = 0; r < 4; ++r) {
                partial += qr[r] * b2f(k0[r]) * acc[mb][0][r]
                         + qr[4 + r] * b2f(k1[r]) * acc[mb][1][r];
            }
            partial += __shfl_xor(partial, 16);
            partial += __shfl_xor(partial, 32);
            if (lg == 0) scb2[w * MT + m] = partial;
        }

        // phase 5: wave-local online softmax for head w
        {
            const float s = scb2[w * MT + lane];
            float tmax = s;
            #pragma unroll
            for (int msk = 1; msk < 64; msk <<= 1) tmax = fmaxf(tmax, __shfl_xor(tmax, msk));
            const float mnew = fmaxf(m_run, tmax);
            const float corr = __expf(m_run - mnew);
            const float e = __expf(s - mnew);
            scb2[w * MT + lane] = e;
            float ss = e;
            #pragma unroll
            for (int msk = 1; msk < 64; msk <<= 1) ss += __shfl_xor(ss, msk);
            l_run = l_run * corr + ss;
            m_run = mnew;
            if (lane == 0) corrS[w] = corr;
        }
        __syncthreads();                  // (D) weights + corrS visible

        // phase 6: PV partials from vS (swizzled scalar reads, conflict-free).
        // thread: c = t&255, m-half = t>>8
        {
            const int c = t & 255, half = t >> 8;
            const int h = c >> 5;
            const int cx = c * 2;
            const char* vb = vS + (half * 32) * 512;
            const float* wr2 = scb2 + h * MT + half * 32;
            float s = 0.f;
            #pragma unroll
            for (int i = 0; i < 8; ++i) {
                const float4 wa = *(const float4*)(wr2 + i * 4);
                const int mb4 = i * 4;
                s += wa.x * b2f(*(const short*)(vb + (mb4 + 0) * 512 + (cx ^ (((mb4 + 0) & 7) << 4))))
                   + wa.y * b2f(*(const short*)(vb + (mb4 + 1) * 512 + (cx ^ (((mb4 + 1) & 7) << 4))))
                   + wa.z * b2f(*(const short*)(vb + (mb4 + 2) * 512 + (cx ^ (((mb4 + 2) & 7) << 4))))
                   + wa.w * b2f(*(const short*)(vb + (mb4 + 3) * 512 + (cx ^ (((mb4 + 3) & 7) << 4))));
            }
            pacc[t] = s;
        }
        __syncthreads();                  // (E) pacc visible
        if (t < 256) xacc = xacc * corrS[t >> 5] + pacc[t] + pacc[t + 256];
    }

    // epilogue: finish softmax norm, then fused out-projection + residual
    if (lane == 0) lS[w] = l_run;
    __syncthreads();
    if (t < 256) scb2[t] = xacc / lS[t >> 5];    // x vector (256 f32)
    __syncthreads();
    {
        const int j = t & 255, half = t >> 8;
        const float* wr = Wo + (size_t)j * Cn + half * 128;
        const float* xb = scb2 + half * 128;
        float s = 0.f;
        for (int k = 0; k < 128; k += 4) {
            const float4 wv = *(const float4*)(wr + k);
            s += xb[k] * wv.x + xb[k+1] * wv.y + xb[k+2] * wv.z + xb[k+3] * wv.w;
        }
        pacc[t] = s;
    }
    __syncthreads();
    if (t < 256)
        xout[(size_t)qrow * Cn + t] = pacc[t] + pacc[t + 256] + bo[t]
                                    + query[(size_t)qrow * Cn + t];
}

extern "C" void kernel_launch(void* const* d_in, const int* in_sizes, int n_in,
                              void* d_out, int out_size, void* d_ws, size_t ws_size,
                              hipStream_t stream) {
    const float* query = (const float*)d_in[0];
    const float* key   = (const float*)d_in[1];
    const float* qpos  = (const float*)d_in[2];
    const float* Wq    = (const float*)d_in[3];
    const float* bq    = (const float*)d_in[4];
    const float* Wk    = (const float*)d_in[5];
    const float* Wv    = (const float*)d_in[6];
    const float* bv    = (const float*)d_in[7];
    const float* Wo    = (const float*)d_in[8];
    const float* bo    = (const float*)d_in[9];
    const float* W1    = (const float*)d_in[10];
    const float* b1    = (const float*)d_in[11];
    const float* W2    = (const float*)d_in[12];
    const float* b2    = (const float*)d_in[13];
    const float* freqs = (const float*)d_in[14];
    float* out = (float*)d_out;

    char* ws = (char*)d_ws;
    float* qp  = (float*)(ws);                 // 512 KB  (B*N*C f32)
    short* kpb = (short*)(ws + 524288);        // 512 KB  (B*M*C bf16, row-swizzled)
    short* vpb = (short*)(ws + 1048576);       // 512 KB  (B*M*C bf16, row-swizzled)
    short* W1b = (short*)(ws + 1572864);       // 128 KB bf16
    short* W2b = (short*)(ws + 1703936);       // 128 KB bf16

    prep<<<1024, 256, 0, stream>>>(query, key, Wq, bq, Wk, Wv, bv, W1, W2,
                                   W1b, W2b, qp, kpb, vpb);
    fused_attn<<<Bn * Nn, 512, 0, stream>>>(qp, kpb, vpb, qpos, W1b, W2b,
                                            b1, b2, freqs, Wo, bo, query, out);
}

// Round 10
// 295.866 us; speedup vs baseline: 1.5511x; 1.1013x over previous
//
#include <hip/hip_runtime.h>

// Problem constants (fixed by the reference)
#define Bn 2
#define Nn 256
#define Mn 512
#define Cn 256
#define Hn 8
#define MT 128            // m-tile size in fused kernel (4 tiles)
#define SCALE_ 0.17677669529663687f   // Dh^-0.5, Dh=32
#define INV2PI 0.15915494309189535f

typedef short bf16x8 __attribute__((ext_vector_type(8)));
typedef short bf16x4 __attribute__((ext_vector_type(4)));
typedef float f32x4 __attribute__((ext_vector_type(4)));

static __device__ __forceinline__ float b2f(short s) {
    unsigned u = ((unsigned)(unsigned short)s) << 16;
    return __builtin_bit_cast(float, u);
}
static __device__ __forceinline__ short f2b(float f) {   // RNE f32->bf16
    unsigned u = __builtin_bit_cast(unsigned, f);
    u += 0x7fffu + ((u >> 16) & 1u);
    return (short)(u >> 16);
}
static __device__ __forceinline__ void async16(const void* g, void* l) {
    __builtin_amdgcn_global_load_lds(
        (const __attribute__((address_space(1))) unsigned int*)g,
        (__attribute__((address_space(3))) unsigned int*)l, 16, 0, 0);
}

// ---- prep2: W1/W2 convert (vectorized) + k'/v' projections ----
// bid 0..63: convert (8 elems/thread). 64..319: k' (swizzled [b][m][c] bf16).
// 320..575: v' (plain [b][m][c] bf16).
__global__ __launch_bounds__(256) void prep2(
        const float* __restrict__ key, const float* __restrict__ Wk,
        const float* __restrict__ Wv, const float* __restrict__ bv,
        const float* __restrict__ W1, const float* __restrict__ W2,
        short* __restrict__ W1b, short* __restrict__ W2b,
        short* __restrict__ kpb, short* __restrict__ vpb) {
    __shared__ float arow[32][Cn];
    const int bid = blockIdx.x;
    const int t = threadIdx.x;
    if (bid < 64) {                        // convert W1/W2 to bf16, 8/thread
        const int half = bid >> 5;
        const int off = (bid & 31) * 2048 + t * 8;
        const float* src = half ? W2 : W1;
        short* dst = half ? W2b : W1b;
        const float4 a = *(const float4*)(src + off);
        const float4 c = *(const float4*)(src + off + 4);
        bf16x8 p;
        p[0] = f2b(a.x); p[1] = f2b(a.y); p[2] = f2b(a.z); p[3] = f2b(a.w);
        p[4] = f2b(c.x); p[5] = f2b(c.y); p[6] = f2b(c.z); p[7] = f2b(c.w);
        *(bf16x8*)(dst + off) = p;
        return;
    }
    const int isv = bid >= 320;
    const int id = bid - (isv ? 320 : 64);
    const int r0 = (id >> 3) * 32, c0 = (id & 7) * 32;
    const float* W = isv ? Wv : Wk;
    #pragma unroll
    for (int i = 0; i < 32; ++i) arow[i][t] = key[(size_t)(r0 + i) * Cn + t];
    __syncthreads();
    const int col = c0 + (t & 31);
    const int rs = t >> 5;                 // 8 slots x 4 rows
    float a4[4] = {0.f, 0.f, 0.f, 0.f};
    const float* wr = W + (size_t)col * Cn;
    for (int k = 0; k < Cn; k += 4) {
        const float4 wv = *(const float4*)(wr + k);
        #pragma unroll
        for (int i = 0; i < 4; ++i) {
            const int r = rs * 4 + i;
            a4[i] += arow[r][k] * wv.x + arow[r][k+1] * wv.y
                   + arow[r][k+2] * wv.z + arow[r][k+3] * wv.w;
        }
    }
    if (!isv) {                            // k': swizzled rows (matches async16+ds_read)
        const int bk = r0 >> 9, mm0 = (r0 & 511) + rs * 4;
        char* base = (char*)kpb + (size_t)bk * Mn * Cn * 2;
        #pragma unroll
        for (int i = 0; i < 4; ++i) {
            const int m = mm0 + i;
            *(short*)(base + m * 512 + ((col * 2) ^ ((m & 7) << 4))) = f2b(a4[i]);
        }
    } else {                               // v': plain [m][c]
        const float bvv = bv[col];
        #pragma unroll
        for (int i = 0; i < 4; ++i)
            vpb[(size_t)(r0 + rs * 4 + i) * Cn + col] = f2b(a4[i] + bvv);
    }
}

// ---- fused: q'-proj + MLP + gated scores + softmax + PV + out-proj ----
// 512 threads = 8 waves; wave w owns channel slice [w*32,w*32+32) == head w.
// MT=128 (4 tiles): half the barriers per unit work vs MT=64.
// LDS ~138.6 KB -> 1 block/CU. Time-shared wreg[16] (64 VGPRs); W-table
// offsets opacified per-tile so the compiler cannot hoist W2 loads.
__global__ __launch_bounds__(512, 1) void fused_attn(
        const float* __restrict__ query, const float* __restrict__ Wq,
        const float* __restrict__ bq, const short* __restrict__ kpb,
        const short* __restrict__ vpb, const float* __restrict__ qpos,
        const short* __restrict__ W1b, const short* __restrict__ W2b,
        const float* __restrict__ b1, const float* __restrict__ b2,
        const float* __restrict__ freqs, const float* __restrict__ Wo,
        const float* __restrict__ bo, float* __restrict__ xout) {
    __shared__ __align__(16) char embS[MT * 512];   // 64 KB emb/S, XOR-swizzled
    __shared__ __align__(16) char kS[MT * 512];     // 64 KB K tile bf16 [m][c] swz
    __shared__ float tposS[Mn];                     // 2 KB qpos row
    __shared__ float fbuf[128];                     // freqs / 2pi
    __shared__ float qbuf[Cn];                      // q' row, pre-scaled
    __shared__ float b2buf[Cn];
    __shared__ float scb2[Hn * MT];                 // 4 KB scores -> weights -> x
    __shared__ float pacc[512];
    __shared__ float corrS[Hn], lS[Hn];

    const int t = threadIdx.x;
    const int lane = t & 63;
    const int w = t >> 6;                 // wave id = head id = col-slice id
    const int lr = lane & 15, lg = lane >> 4;

    // XCD-chunked bijective swizzle: 512 blocks = 8 XCDs x 64 contiguous
    const int qrow = ((blockIdx.x & 7) << 6) | (blockIdx.x >> 3);
    const int b = qrow >> 8;              // batch

    const int cA = w * 32 + lr, cB = cA + 16;
    const short* w1p0 = W1b + (size_t)cA * Cn + lg * 8;
    const short* w1p1 = W1b + (size_t)cB * Cn + lg * 8;
    const short* w2p0 = W2b + (size_t)cA * Cn + lg * 8;
    const short* w2p1 = W2b + (size_t)cB * Cn + lg * 8;
    const float b1v0 = b1[cA], b1v1 = b1[cB];

    // ---- prologue: stage constants, compute q' row (GEMV) into qbuf ----
    tposS[t] = qpos[(size_t)qrow * Mn + t];
    if (t < 128) fbuf[t] = freqs[t] * INV2PI;
    if (t < 256) {
        b2buf[t] = b2[t];
        scb2[t] = query[(size_t)qrow * Cn + t];   // temp stage of query row
    }
    __syncthreads();
    {
        const int c = t & 255, half = t >> 8;
        const float* wr = Wq + (size_t)c * Cn + half * 128;
        const float* xb = scb2 + half * 128;
        float s = 0.f;
        for (int k = 0; k < 128; k += 4) {
            const float4 wv = *(const float4*)(wr + k);
            s += xb[k] * wv.x + xb[k+1] * wv.y + xb[k+2] * wv.z + xb[k+3] * wv.w;
        }
        pacc[t] = s;
    }
    __syncthreads();
    if (t < 256) qbuf[t] = (pacc[t] + pacc[t + 256] + bq[t]) * SCALE_;

    float m_run = -1e30f, l_run = 0.f;
    float xacc = 0.f;                     // t<256: output channel t
    bf16x8 wreg[16];                      // time-shared W fragment buffer

    for (int m0 = 0; m0 < Mn; m0 += MT) {
        // issue async K tile (linear LDS dest; global rows pre-swizzled)
        {
            const size_t tbase = ((size_t)(b * Mn + m0)) * Cn * 2;   // bytes
            #pragma unroll
            for (int i = 0; i < 8; ++i) {
                const int seg = (i * 8 + w) * 1024;
                async16((const char*)kpb + tbase + seg + lane * 16, kS + seg);
            }
        }

        // phase 1: embeddings -> embS. thread: m = t>>2, freq group fq = t&3 (32 f)
        {
            const int m = t >> 2, fq = t & 3;
            const float tv = tposS[m0 + m];
            char* rowp = embS + m * 512;
            const int sw = (m & 7) << 4;
            #pragma unroll
            for (int j8 = 0; j8 < 4; ++j8) {
                bf16x8 pc, ps;
                #pragma unroll
                for (int e = 0; e < 8; ++e) {
                    const float xr = tv * fbuf[fq * 32 + j8 * 8 + e];
                    pc[e] = f2b(__builtin_amdgcn_cosf(xr));
                    ps[e] = f2b(__builtin_amdgcn_sinf(xr));
                }
                *(bf16x8*)(rowp + ((fq * 64 + j8 * 16) ^ sw)) = pc;        // cos
                *(bf16x8*)(rowp + ((256 + fq * 64 + j8 * 16) ^ sw)) = ps;  // sin
            }
        }
        __syncthreads();                  // (A) emb + staged K visible; qbuf ready

        // phase 2: GEMM1  hidden = emb @ W1^T   (wreg <- W1, opacified offset)
        {
            int woff = 0;
            asm volatile("" : "+v"(woff));
            #pragma unroll
            for (int kk = 0; kk < 8; ++kk) {
                wreg[kk] = *(const bf16x8*)(w1p0 + woff + kk * 32);
                wreg[8 + kk] = *(const bf16x8*)(w1p1 + woff + kk * 32);
            }
        }
        f32x4 acc[8][2];
        #pragma unroll
        for (int pb = 0; pb < 8; ++pb) {
            acc[pb][0] = (f32x4){0.f, 0.f, 0.f, 0.f};
            acc[pb][1] = (f32x4){0.f, 0.f, 0.f, 0.f};
        }
        #pragma unroll
        for (int pb = 0; pb < 8; ++pb) {
            const int row = pb * 16 + lr;
            const int sw = (row & 7) << 4;
            const char* rowp = embS + row * 512;
            #pragma unroll
            for (int kk = 0; kk < 8; ++kk) {
                const bf16x8 a = *(const bf16x8*)(rowp + ((lg * 16 + kk * 64) ^ sw));
                acc[pb][0] = __builtin_amdgcn_mfma_f32_16x16x32_bf16(a, wreg[kk],     acc[pb][0], 0, 0, 0);
                acc[pb][1] = __builtin_amdgcn_mfma_f32_16x16x32_bf16(a, wreg[8 + kk], acc[pb][1], 0, 0, 0);
            }
        }
        __syncthreads();                  // (B) all emb reads done

        // store S = silu(hidden + b1) into embS (swizzled)
        #pragma unroll
        for (int pb = 0; pb < 8; ++pb) {
            #pragma unroll
            for (int jb = 0; jb < 2; ++jb) {
                const float bv = jb ? b1v1 : b1v0;
                const int j = w * 32 + jb * 16 + lr;
                #pragma unroll
                for (int r = 0; r < 4; ++r) {
                    const int row = pb * 16 + lg * 4 + r;   // C/D: row = 4*(lane>>4)+reg
                    float hv = acc[pb][jb][r] + bv;
                    hv = hv / (1.f + __expf(-hv));
                    *(short*)(embS + row * 512 + ((j * 2) ^ ((row & 7) << 4))) = f2b(hv);
                }
            }
        }
        __syncthreads();                  // (C) S visible

        // phase 3: SWAPPED GEMM2  D2 = W2slice @ S^T  (wreg <- W2, opacified)
        {
            int woff = 0;
            asm volatile("" : "+v"(woff));
            #pragma unroll
            for (int kk = 0; kk < 8; ++kk) {
                wreg[kk] = *(const bf16x8*)(w2p0 + woff + kk * 32);
                wreg[8 + kk] = *(const bf16x8*)(w2p1 + woff + kk * 32);
            }
        }
        // acc init = b2 (lane mapping i=cb*4+r -> c = w*32+cb*16+lg*4+r)
        {
            float b2a[8];
            #pragma unroll
            for (int i = 0; i < 8; ++i)
                b2a[i] = b2buf[w * 32 + (i >> 2) * 16 + lg * 4 + (i & 3)];
            #pragma unroll
            for (int mb = 0; mb < 8; ++mb)
                #pragma unroll
                for (int cb = 0; cb < 2; ++cb)
                    #pragma unroll
                    for (int r = 0; r < 4; ++r)
                        acc[mb][cb][r] = b2a[cb * 4 + r];
        }
        #pragma unroll
        for (int mb = 0; mb < 8; ++mb) {
            const int row = mb * 16 + lr;
            const int sw = (row & 7) << 4;
            const char* rowp = embS + row * 512;
            #pragma unroll
            for (int kk = 0; kk < 8; ++kk) {
                const bf16x8 a = *(const bf16x8*)(rowp + ((lg * 16 + kk * 64) ^ sw));
                acc[mb][0] = __builtin_amdgcn_mfma_f32_16x16x32_bf16(wreg[kk],     a, acc[mb][0], 0, 0, 0);
                acc[mb][1] = __builtin_amdgcn_mfma_f32_16x16x32_bf16(wreg[8 + kk], a, acc[mb][1], 0, 0, 0);
            }
        }

        // phase 4: s[m] = sum_c q[c]*k[m][c]*D2[c][m]; K from kS; 2-shuffle reduce
        {
            float qa[8];
            #pragma unroll
            for (int i = 0; i < 8; ++i)
                qa[i] = qbuf[w * 32 + (i >> 2) * 16 + lg * 4 + (i & 3)];
            #pragma unroll
            for (int mb = 0; mb < 8; ++mb) {
                const int m = mb * 16 + lr;
                const int sw = (m & 7) << 4;
                const char* kr = kS + m * 512;
                const int cc0 = (w * 32 + lg * 4) * 2;
                const bf16x4 k0 = *(const bf16x4*)(kr + (cc0 ^ sw));
                const bf16x4 k1 = *(const bf16x4*)(kr + ((cc0 + 32) ^ sw));
                float partial = 0.f;
                #pragma unroll
                for (int r = 0; r < 4; ++r) {
                    partial += qa[r] * b2f(k0[r]) * acc[mb][0][r]
                             + qa[4 + r] * b2f(k1[r]) * acc[mb][1][r];
                }
                partial += __shfl_xor(partial, 16);
                partial += __shfl_xor(partial, 32);
                if (lg == 0) scb2[w * MT + m] = partial;
            }
        }

        // phase 5: wave-local online softmax for head w (128 scores)
        {
            const float s0 = scb2[w * MT + lane];
            const float s1 = scb2[w * MT + 64 + lane];
            float tmax = fmaxf(s0, s1);
            #pragma unroll
            for (int msk = 1; msk < 64; msk <<= 1) tmax = fmaxf(tmax, __shfl_xor(tmax, msk));
            const float mnew = fmaxf(m_run, tmax);
            const float corr = __expf(m_run - mnew);
            const float e0 = __expf(s0 - mnew);
            const float e1 = __expf(s1 - mnew);
            scb2[w * MT + lane] = e0;
            scb2[w * MT + 64 + lane] = e1;
            float ss = e0 + e1;
            #pragma unroll
            for (int msk = 1; msk < 64; msk <<= 1) ss += __shfl_xor(ss, msk);
            l_run = l_run * corr + ss;
            m_run = mnew;
            if (lane == 0) corrS[w] = corr;
        }
        __syncthreads();                  // (D) weights + corrS visible

        // phase 6: PV partials; V direct from L2 (coalesced over c).
        // thread: c = t&255, m-half = t>>8 (64 m each)
        {
            const int c = t & 255, half = t >> 8;
            const int h = c >> 5;
            const short* vrow = vpb + ((size_t)(b * Mn + m0 + half * 64)) * Cn + c;
            const float* wr2 = scb2 + h * MT + half * 64;
            float s = 0.f;
            #pragma unroll
            for (int i = 0; i < 16; ++i) {
                const float4 wa = *(const float4*)(wr2 + i * 4);
                s += wa.x * b2f(vrow[(size_t)(i * 4 + 0) * Cn])
                   + wa.y * b2f(vrow[(size_t)(i * 4 + 1) * Cn])
                   + wa.z * b2f(vrow[(size_t)(i * 4 + 2) * Cn])
                   + wa.w * b2f(vrow[(size_t)(i * 4 + 3) * Cn]);
            }
            pacc[t] = s;
        }
        __syncthreads();                  // (E) pacc visible
        if (t < 256) xacc = xacc * corrS[t >> 5] + pacc[t] + pacc[t + 256];
    }

    // epilogue: softmax norm, fused out-projection + bias + residual
    if (lane == 0) lS[w] = l_run;
    __syncthreads();
    if (t < 256) scb2[t] = xacc / lS[t >> 5];    // x vector (256 f32)
    __syncthreads();
    {
        const int j = t & 255, half = t >> 8;
        const float* wr = Wo + (size_t)j * Cn + half * 128;
        const float* xb = scb2 + half * 128;
        float s = 0.f;
        for (int k = 0; k < 128; k += 4) {
            const float4 wv = *(const float4*)(wr + k);
            s += xb[k] * wv.x + xb[k+1] * wv.y + xb[k+2] * wv.z + xb[k+3] * wv.w;
        }
        pacc[t] = s;
    }
    __syncthreads();
    if (t < 256)
        xout[(size_t)qrow * Cn + t] = pacc[t] + pacc[t + 256] + bo[t]
                                    + query[(size_t)qrow * Cn + t];
}

extern "C" void kernel_launch(void* const* d_in, const int* in_sizes, int n_in,
                              void* d_out, int out_size, void* d_ws, size_t ws_size,
                              hipStream_t stream) {
    const float* query = (const float*)d_in[0];
    const float* key   = (const float*)d_in[1];
    const float* qpos  = (const float*)d_in[2];
    const float* Wq    = (const float*)d_in[3];
    const float* bq    = (const float*)d_in[4];
    const float* Wk    = (const float*)d_in[5];
    const float* Wv    = (const float*)d_in[6];
    const float* bv    = (const float*)d_in[7];
    const float* Wo    = (const float*)d_in[8];
    const float* bo    = (const float*)d_in[9];
    const float* W1    = (const float*)d_in[10];
    const float* b1    = (const float*)d_in[11];
    const float* W2    = (const float*)d_in[12];
    const float* b2    = (const float*)d_in[13];
    const float* freqs = (const float*)d_in[14];
    float* out = (float*)d_out;

    char* ws = (char*)d_ws;
    short* kpb = (short*)(ws);                 // 512 KB  (B*M*C bf16, row-swizzled)
    short* vpb = (short*)(ws + 524288);        // 512 KB  (B*M*C bf16, plain)
    short* W1b = (short*)(ws + 1048576);       // 128 KB bf16
    short* W2b = (short*)(ws + 1179648);       // 128 KB bf16

    prep2<<<576, 256, 0, stream>>>(key, Wk, Wv, bv, W1, W2, W1b, W2b, kpb, vpb);
    fused_attn<<<Bn * Nn, 512, 0, stream>>>(query, Wq, bq, kpb, vpb, qpos,
                                            W1b, W2b, b1, b2, freqs, Wo, bo, out);
}